// Round 2
// baseline (526.613 us; speedup 1.0000x reference)
//
#include <hip/hip_runtime.h>

#define B_ 32
#define S_ 2048
#define H_ 1024
#define NSEG 16

typedef __attribute__((ext_vector_type(4))) float f32x4;

// Kernel 1: v[b,h] = sum_k h_t[b,k] * W[k,h]   (v = h_t @ W)
__global__ __launch_bounds__(256) void k_v(const float* __restrict__ h_t,
                                           const float* __restrict__ W,
                                           float* __restrict__ v) {
    __shared__ float sh[H_];
    int b = blockIdx.x;
    int h = blockIdx.y * 256 + threadIdx.x;
    for (int i = threadIdx.x; i < H_; i += 256) sh[i] = h_t[b * H_ + i];
    __syncthreads();
    float acc = 0.f;
    #pragma unroll 4
    for (int k = 0; k < H_; ++k) acc = fmaf(sh[k], W[(size_t)k * H_ + h], acc);
    v[b * H_ + h] = acc;
}

// Kernel 2: scores[b,s] = dot(cntx[b,s,:], v[b,:])  — one wave per (b,s)
__global__ __launch_bounds__(256) void k_scores(const float* __restrict__ cntx,
                                                const float* __restrict__ v,
                                                float* __restrict__ scores) {
    int w = blockIdx.x * 4 + (threadIdx.x >> 6);   // global wave id = b*S_+s
    int lane = threadIdx.x & 63;
    int b = w >> 11;                               // S_ = 2048
    const f32x4* p  = (const f32x4*)(cntx + (size_t)w * H_ + lane * 16);
    const f32x4* pv = (const f32x4*)(v + b * H_ + lane * 16);
    float acc = 0.f;
    #pragma unroll
    for (int q = 0; q < 4; ++q) {
        f32x4 c = p[q];
        f32x4 vv = pv[q];
        #pragma unroll
        for (int j = 0; j < 4; ++j) acc = fmaf(c[j], vv[j], acc);
    }
    #pragma unroll
    for (int off = 32; off; off >>= 1) acc += __shfl_down(acc, off);
    if (lane == 0) scores[w] = acc;
}

// Kernel 3: softmax over s for each b (in-place on scores -> attn)
__global__ __launch_bounds__(256) void k_softmax(float* __restrict__ sc) {
    int b = blockIdx.x;
    float* p = sc + b * S_;
    int t = threadIdx.x;
    int wid = t >> 6, lane = t & 63;
    float vals[8];
    float lmax = -1e30f;
    #pragma unroll
    for (int i = 0; i < 8; ++i) { vals[i] = p[t + i * 256]; lmax = fmaxf(lmax, vals[i]); }
    #pragma unroll
    for (int off = 32; off; off >>= 1) lmax = fmaxf(lmax, __shfl_down(lmax, off));
    __shared__ float redm[4];
    __shared__ float reds[4];
    if (lane == 0) redm[wid] = lmax;
    __syncthreads();
    float gmax = fmaxf(fmaxf(redm[0], redm[1]), fmaxf(redm[2], redm[3]));
    float lsum = 0.f;
    #pragma unroll
    for (int i = 0; i < 8; ++i) { vals[i] = __expf(vals[i] - gmax); lsum += vals[i]; }
    #pragma unroll
    for (int off = 32; off; off >>= 1) lsum += __shfl_down(lsum, off);
    if (lane == 0) reds[wid] = lsum;
    __syncthreads();
    float ginv = 1.f / (reds[0] + reds[1] + reds[2] + reds[3]);
    #pragma unroll
    for (int i = 0; i < 8; ++i) p[t + i * 256] = vals[i] * ginv;
}

// Kernel 4: partial[b,seg,h] = sum_{s in seg} attn[b,s] * cntx[b,s,h]
__global__ __launch_bounds__(256) void k_wsum(const float* __restrict__ cntx,
                                              const float* __restrict__ attn,
                                              float* __restrict__ partial) {
    int b = blockIdx.x, seg = blockIdx.y;
    const int scount = S_ / NSEG;             // 128
    int s0 = seg * scount;
    __shared__ float sa[scount];
    if (threadIdx.x < scount) sa[threadIdx.x] = attn[b * S_ + s0 + threadIdx.x];
    __syncthreads();
    int h0 = threadIdx.x * 4;                 // 256 threads * 4 = 1024 = H_
    f32x4 acc = {0.f, 0.f, 0.f, 0.f};
    const float* base = cntx + ((size_t)b * S_ + s0) * H_ + h0;
    #pragma unroll 4
    for (int s = 0; s < scount; ++s) {
        float a = sa[s];
        f32x4 c = *(const f32x4*)(base + (size_t)s * H_);
        #pragma unroll
        for (int j = 0; j < 4; ++j) acc[j] = fmaf(a, c[j], acc[j]);
    }
    *(f32x4*)(partial + (size_t)(b * NSEG + seg) * H_ + h0) = acc;
}

// Kernel 5: out[b,h] = alpha*h_t[b,h] + beta*sum_seg partial[b,seg,h]
__global__ __launch_bounds__(256) void k_final(const float* __restrict__ h_t,
                                               const float* __restrict__ partial,
                                               const float* __restrict__ alpha,
                                               const float* __restrict__ beta,
                                               float* __restrict__ out) {
    int idx = blockIdx.x * 256 + threadIdx.x;  // B_*H_ = 32768
    int b = idx >> 10, h = idx & 1023;
    float a = alpha[0], be = beta[0];
    float s = 0.f;
    #pragma unroll
    for (int g = 0; g < NSEG; ++g) s += partial[(size_t)(b * NSEG + g) * H_ + h];
    out[idx] = fmaf(a, h_t[idx], be * s);
}

extern "C" void kernel_launch(void* const* d_in, const int* in_sizes, int n_in,
                              void* d_out, int out_size, void* d_ws, size_t ws_size,
                              hipStream_t stream) {
    const float* h_t   = (const float*)d_in[0];
    const float* cntx  = (const float*)d_in[1];
    const float* W     = (const float*)d_in[2];
    const float* alpha = (const float*)d_in[3];
    const float* beta  = (const float*)d_in[4];
    float* out = (float*)d_out;

    float* v       = (float*)d_ws;                       // 32768 floats
    float* scores  = v + B_ * H_;                        // 65536 floats
    float* partial = scores + B_ * S_;                   // 524288 floats (total ws 2.43 MB)

    k_v<<<dim3(B_, H_ / 256), 256, 0, stream>>>(h_t, W, v);
    k_scores<<<dim3(B_ * S_ / 4), 256, 0, stream>>>(cntx, v, scores);
    k_softmax<<<dim3(B_), 256, 0, stream>>>(scores);
    k_wsum<<<dim3(B_, NSEG), 256, 0, stream>>>(cntx, scores, partial);
    k_final<<<dim3(B_ * H_ / 256), 256, 0, stream>>>(h_t, partial, alpha, beta, out);
}

// Round 3
// 386.286 us; speedup vs baseline: 1.3633x; 1.3633x over previous
//
#include <hip/hip_runtime.h>

#define B_ 32
#define S_ 2048
#define H_ 1024
#define NCHUNK 64                 // chunks per batch row; one wave per (b, chunk)
#define ROWS (S_ / NCHUNK)        // 32 s-rows per wave

typedef __attribute__((ext_vector_type(4))) float f32x4;

// ---------------------------------------------------------------------------
// Kernel 1: vpart[ks][b][h] = sum_{k in ks-chunk} h_t[b,k] * W[k,h]
// Split-K (4 chunks of 256) to break the serial FMA chain and raise occupancy.
// grid (B, H/256, 4), block 256.
__global__ __launch_bounds__(256) void k_v(const float* __restrict__ h_t,
                                           const float* __restrict__ W,
                                           float* __restrict__ vpart) {
    __shared__ float sh[256];
    int b = blockIdx.x, hb = blockIdx.y, ks = blockIdx.z;
    int h = hb * 256 + threadIdx.x;
    sh[threadIdx.x] = h_t[b * H_ + ks * 256 + threadIdx.x];
    __syncthreads();
    const float* wp = W + (size_t)(ks * 256) * H_ + h;
    float a0 = 0.f, a1 = 0.f, a2 = 0.f, a3 = 0.f;
    #pragma unroll 4
    for (int k = 0; k < 256; k += 4) {
        a0 = fmaf(sh[k],     wp[(size_t)k * H_],        a0);
        a1 = fmaf(sh[k + 1], wp[(size_t)(k + 1) * H_],  a1);
        a2 = fmaf(sh[k + 2], wp[(size_t)(k + 2) * H_],  a2);
        a3 = fmaf(sh[k + 3], wp[(size_t)(k + 3) * H_],  a3);
    }
    vpart[((size_t)ks * B_ + b) * H_ + h] = (a0 + a1) + (a2 + a3);
}

// ---------------------------------------------------------------------------
// Kernel 2: fused flash pass. One wave per (b, chunk): for each s-row,
// score = c·v (butterfly reduce), online softmax, acc = acc*alpha + p*c.
// cntx is read exactly once. Lane layout h = q*256 + lane*4 so every
// global_load_dwordx4 is a fully-coalesced 1 KB wave transaction.
__global__ __launch_bounds__(256) void k_flash(const float* __restrict__ cntx,
                                               const float* __restrict__ vpart,
                                               float* __restrict__ partO,
                                               float* __restrict__ stats) {
    int gw   = blockIdx.x * 4 + (threadIdx.x >> 6);   // wave id in [0, B_*NCHUNK)
    int lane = threadIdx.x & 63;
    int b    = gw >> 6;                                // NCHUNK = 64
    int ch   = gw & 63;

    // v fragment: vv[q] covers h = q*256 + lane*4 .. +3; sum the 4 k-split partials
    f32x4 vv[4];
    #pragma unroll
    for (int q = 0; q < 4; ++q) {
        f32x4 t0 = *(const f32x4*)(vpart + ((size_t)0 * B_ + b) * H_ + q * 256 + lane * 4);
        f32x4 t1 = *(const f32x4*)(vpart + ((size_t)1 * B_ + b) * H_ + q * 256 + lane * 4);
        f32x4 t2 = *(const f32x4*)(vpart + ((size_t)2 * B_ + b) * H_ + q * 256 + lane * 4);
        f32x4 t3 = *(const f32x4*)(vpart + ((size_t)3 * B_ + b) * H_ + q * 256 + lane * 4);
        vv[q] = (t0 + t1) + (t2 + t3);
    }

    const float* base = cntx + ((size_t)b * S_ + (size_t)ch * ROWS) * H_;
    f32x4 acc[4];
    #pragma unroll
    for (int q = 0; q < 4; ++q) acc[q] = (f32x4){0.f, 0.f, 0.f, 0.f};
    float m = -1e30f, l = 0.f;

    for (int s = 0; s < ROWS; ++s) {
        f32x4 c[4];
        #pragma unroll
        for (int q = 0; q < 4; ++q)
            c[q] = *(const f32x4*)(base + (size_t)s * H_ + q * 256 + lane * 4);
        float d = 0.f;
        #pragma unroll
        for (int q = 0; q < 4; ++q)
            #pragma unroll
            for (int j = 0; j < 4; ++j) d = fmaf(c[q][j], vv[q][j], d);
        #pragma unroll
        for (int off = 32; off; off >>= 1) d += __shfl_xor(d, off);

        float mn = fmaxf(m, d);
        float al = __expf(m - mn);     // first iter: exp(-1e30 - d) = 0, kills stale acc
        float p  = __expf(d - mn);
        l = fmaf(l, al, p);
        #pragma unroll
        for (int q = 0; q < 4; ++q)
            #pragma unroll
            for (int j = 0; j < 4; ++j)
                acc[q][j] = fmaf(acc[q][j], al, p * c[q][j]);
        m = mn;
    }

    float* po = partO + (size_t)gw * H_;
    #pragma unroll
    for (int q = 0; q < 4; ++q) *(f32x4*)(po + q * 256 + lane * 4) = acc[q];
    if (lane == 0) { stats[gw * 2] = m; stats[gw * 2 + 1] = l; }
}

// ---------------------------------------------------------------------------
// Kernel 3: combine chunk partials with their (m,l) stats + final blend.
// grid (B, H/256), block 256.
__global__ __launch_bounds__(256) void k_combine(const float* __restrict__ h_t,
                                                 const float* __restrict__ partO,
                                                 const float* __restrict__ stats,
                                                 const float* __restrict__ alpha,
                                                 const float* __restrict__ beta,
                                                 float* __restrict__ out) {
    int b = blockIdx.x, hb = blockIdx.y;
    int t = threadIdx.x;
    __shared__ float sw[NCHUNK];
    __shared__ float sden;
    if (t < NCHUNK) {
        float mg = stats[(b * NCHUNK + t) * 2];
        float lg = stats[(b * NCHUNK + t) * 2 + 1];
        float M = mg;
        #pragma unroll
        for (int off = 32; off; off >>= 1) M = fmaxf(M, __shfl_xor(M, off));
        float w = __expf(mg - M);
        sw[t] = w;
        float d = w * lg;
        #pragma unroll
        for (int off = 32; off; off >>= 1) d += __shfl_xor(d, off);
        if (t == 0) sden = d;
    }
    __syncthreads();
    int h = hb * 256 + t;
    float sum = 0.f;
    #pragma unroll 8
    for (int g = 0; g < NCHUNK; ++g)
        sum = fmaf(sw[g], partO[(size_t)(b * NCHUNK + g) * H_ + h], sum);
    out[b * H_ + h] = fmaf(alpha[0], h_t[b * H_ + h], beta[0] * (sum / sden));
}

// ---------------------------------------------------------------------------
extern "C" void kernel_launch(void* const* d_in, const int* in_sizes, int n_in,
                              void* d_out, int out_size, void* d_ws, size_t ws_size,
                              hipStream_t stream) {
    const float* h_t   = (const float*)d_in[0];
    const float* cntx  = (const float*)d_in[1];
    const float* W     = (const float*)d_in[2];
    const float* alpha = (const float*)d_in[3];
    const float* beta  = (const float*)d_in[4];
    float* out = (float*)d_out;

    float* vpart = (float*)d_ws;                        // 4*B_*H_      = 131072 floats
    float* partO = vpart + 4 * B_ * H_;                 // B_*NCHUNK*H_ = 2097152 floats
    float* stats = partO + (size_t)B_ * NCHUNK * H_;    // B_*NCHUNK*2  = 4096 floats

    k_v<<<dim3(B_, H_ / 256, 4), 256, 0, stream>>>(h_t, W, vpart);
    k_flash<<<dim3(B_ * NCHUNK / 4), 256, 0, stream>>>(cntx, vpart, partO, stats);
    k_combine<<<dim3(B_, H_ / 256), 256, 0, stream>>>(h_t, partO, stats, alpha, beta, out);
}

// Round 4
// 368.510 us; speedup vs baseline: 1.4290x; 1.0482x over previous
//
#include <hip/hip_runtime.h>

#define B_ 32
#define S_ 2048
#define H_ 1024
#define NCHUNK 128                // chunks per batch row; one wave per (b, chunk)
#define ROWS (S_ / NCHUNK)        // 16 s-rows per wave

typedef __attribute__((ext_vector_type(4))) float f32x4;

// ---------------------------------------------------------------------------
// Kernel 1: vpart[ks][b][h] = sum_{k in ks-chunk} h_t[b,k] * W[k,h]
// Split-K (4 chunks of 256) to break the serial FMA chain.
__global__ __launch_bounds__(256) void k_v(const float* __restrict__ h_t,
                                           const float* __restrict__ W,
                                           float* __restrict__ vpart) {
    __shared__ float sh[256];
    int b = blockIdx.x, hb = blockIdx.y, ks = blockIdx.z;
    int h = hb * 256 + threadIdx.x;
    sh[threadIdx.x] = h_t[b * H_ + ks * 256 + threadIdx.x];
    __syncthreads();
    const float* wp = W + (size_t)(ks * 256) * H_ + h;
    float a0 = 0.f, a1 = 0.f, a2 = 0.f, a3 = 0.f;
    #pragma unroll 4
    for (int k = 0; k < 256; k += 4) {
        a0 = fmaf(sh[k],     wp[(size_t)k * H_],        a0);
        a1 = fmaf(sh[k + 1], wp[(size_t)(k + 1) * H_],  a1);
        a2 = fmaf(sh[k + 2], wp[(size_t)(k + 2) * H_],  a2);
        a3 = fmaf(sh[k + 3], wp[(size_t)(k + 3) * H_],  a3);
    }
    vpart[((size_t)ks * B_ + b) * H_ + h] = (a0 + a1) + (a2 + a3);
}

// ---------------------------------------------------------------------------
// Kernel 2: fused flash pass, software-pipelined. One wave per (b, chunk).
// 4096 waves = 16/CU; prefetch row s+1 while computing row s; nontemporal
// cntx loads (streamed once, no reuse).
__global__ __launch_bounds__(256, 4) void k_flash(const float* __restrict__ cntx,
                                                  const float* __restrict__ vpart,
                                                  float* __restrict__ partO,
                                                  float* __restrict__ stats) {
    int gw   = blockIdx.x * 4 + (threadIdx.x >> 6);   // wave id in [0, B_*NCHUNK)
    int lane = threadIdx.x & 63;
    int b    = gw >> 7;                                // NCHUNK = 128
    int ch   = gw & (NCHUNK - 1);

    // v fragment: vv[q] covers h = q*256 + lane*4 .. +3; sum 4 k-split partials
    f32x4 vv[4];
    #pragma unroll
    for (int q = 0; q < 4; ++q) {
        f32x4 t0 = *(const f32x4*)(vpart + ((size_t)0 * B_ + b) * H_ + q * 256 + lane * 4);
        f32x4 t1 = *(const f32x4*)(vpart + ((size_t)1 * B_ + b) * H_ + q * 256 + lane * 4);
        f32x4 t2 = *(const f32x4*)(vpart + ((size_t)2 * B_ + b) * H_ + q * 256 + lane * 4);
        f32x4 t3 = *(const f32x4*)(vpart + ((size_t)3 * B_ + b) * H_ + q * 256 + lane * 4);
        vv[q] = (t0 + t1) + (t2 + t3);
    }

    const float* rp = cntx + ((size_t)b * S_ + (size_t)ch * ROWS) * H_ + lane * 4;
    f32x4 acc[4];
    #pragma unroll
    for (int q = 0; q < 4; ++q) acc[q] = (f32x4){0.f, 0.f, 0.f, 0.f};
    float m = -1e30f, l = 0.f;

    f32x4 cn[4];
    #pragma unroll
    for (int q = 0; q < 4; ++q)
        cn[q] = __builtin_nontemporal_load((const f32x4*)(rp + q * 256));

    for (int s = 0; s < ROWS; ++s) {
        f32x4 c[4];
        #pragma unroll
        for (int q = 0; q < 4; ++q) c[q] = cn[q];
        if (s + 1 < ROWS) {
            rp += H_;
            #pragma unroll
            for (int q = 0; q < 4; ++q)
                cn[q] = __builtin_nontemporal_load((const f32x4*)(rp + q * 256));
        }
        float d = 0.f;
        #pragma unroll
        for (int q = 0; q < 4; ++q)
            #pragma unroll
            for (int j = 0; j < 4; ++j) d = fmaf(c[q][j], vv[q][j], d);
        #pragma unroll
        for (int off = 32; off; off >>= 1) d += __shfl_xor(d, off);

        float mn = fmaxf(m, d);
        float al = __expf(m - mn);     // first iter: exp(-inf-ish) = 0 kills stale acc
        float p  = __expf(d - mn);
        l = fmaf(l, al, p);
        #pragma unroll
        for (int q = 0; q < 4; ++q)
            #pragma unroll
            for (int j = 0; j < 4; ++j)
                acc[q][j] = fmaf(acc[q][j], al, p * c[q][j]);
        m = mn;
    }

    float* po = partO + (size_t)gw * H_;
    #pragma unroll
    for (int q = 0; q < 4; ++q) *(f32x4*)(po + q * 256 + lane * 4) = acc[q];
    if (lane == 0) { stats[gw * 2] = m; stats[gw * 2 + 1] = l; }
}

// ---------------------------------------------------------------------------
// Kernel 3: combine 128 chunk partials with their (m,l) stats + final blend.
// grid (B, H/256), block 256.
__global__ __launch_bounds__(256) void k_combine(const float* __restrict__ h_t,
                                                 const float* __restrict__ partO,
                                                 const float* __restrict__ stats,
                                                 const float* __restrict__ alpha,
                                                 const float* __restrict__ beta,
                                                 float* __restrict__ out) {
    int b = blockIdx.x, hb = blockIdx.y;
    int t = threadIdx.x;
    int wid = t >> 6;
    __shared__ float sw[NCHUNK];
    __shared__ float redm[2];
    __shared__ float reds[2];
    float mg = 0.f, lg = 0.f;
    if (t < NCHUNK) {                          // waves 0 and 1 exactly
        mg = stats[(b * NCHUNK + t) * 2];
        lg = stats[(b * NCHUNK + t) * 2 + 1];
        float M = mg;
        #pragma unroll
        for (int off = 32; off; off >>= 1) M = fmaxf(M, __shfl_xor(M, off));
        if ((t & 63) == 0) redm[wid] = M;
    }
    __syncthreads();
    float M = fmaxf(redm[0], redm[1]);
    if (t < NCHUNK) {
        float w = __expf(mg - M);
        sw[t] = w;
        float d = w * lg;
        #pragma unroll
        for (int off = 32; off; off >>= 1) d += __shfl_xor(d, off);
        if ((t & 63) == 0) reds[wid] = d;
    }
    __syncthreads();
    float den = reds[0] + reds[1];
    int h = hb * 256 + t;
    float sum = 0.f;
    #pragma unroll 8
    for (int g = 0; g < NCHUNK; ++g)
        sum = fmaf(sw[g], partO[(size_t)(b * NCHUNK + g) * H_ + h], sum);
    out[b * H_ + h] = fmaf(alpha[0], h_t[b * H_ + h], beta[0] * (sum / den));
}

// ---------------------------------------------------------------------------
extern "C" void kernel_launch(void* const* d_in, const int* in_sizes, int n_in,
                              void* d_out, int out_size, void* d_ws, size_t ws_size,
                              hipStream_t stream) {
    const float* h_t   = (const float*)d_in[0];
    const float* cntx  = (const float*)d_in[1];
    const float* W     = (const float*)d_in[2];
    const float* alpha = (const float*)d_in[3];
    const float* beta  = (const float*)d_in[4];
    float* out = (float*)d_out;

    float* vpart = (float*)d_ws;                        // 4*B_*H_      = 131072 floats
    float* partO = vpart + 4 * B_ * H_;                 // B_*NCHUNK*H_ = 4194304 floats
    float* stats = partO + (size_t)B_ * NCHUNK * H_;    // B_*NCHUNK*2  = 8192 floats

    k_v<<<dim3(B_, H_ / 256, 4), 256, 0, stream>>>(h_t, W, vpart);
    k_flash<<<dim3(B_ * NCHUNK / 4), 256, 0, stream>>>(cntx, vpart, partO, stats);
    k_combine<<<dim3(B_, H_ / 256), 256, 0, stream>>>(h_t, partO, stats, alpha, beta, out);
}